// Round 4
// baseline (275.965 us; speedup 1.0000x reference)
//
#include <hip/hip_runtime.h>

// Problem constants (fixed by the reference):
//   img [8192,1024] f32, txt [8192,1024] f32, both l2-normalized
//   set sizes si=st=4, t=16, tts=1, DENOM=2  -> out[bi][bt] = (right+left)/128
#define N_ROWS 8192
#define DIM    1024
#define BOUT   2048
#define BM 256
#define BN 256
#define BK 64
#define KTILES (DIM / BK)   // 16

typedef unsigned short u16;
typedef __attribute__((ext_vector_type(4))) unsigned short u16x4;
typedef __attribute__((ext_vector_type(8))) short short8;   // 8 bf16 MFMA A/B frag
typedef __attribute__((ext_vector_type(16))) float f32x16;  // 32x32 MFMA C/D frag
typedef __attribute__((address_space(3))) u16 lds_u16;

// fp32 -> bf16 round-to-nearest-even
__device__ __forceinline__ u16 f2bf(float f) {
  unsigned u = __float_as_uint(f);
  u += 0x7fffu + ((u >> 16) & 1u);
  return (u16)(u >> 16);
}

__global__ void cast_kernel(const float* __restrict__ a, const float* __restrict__ b,
                            u16* __restrict__ oa, u16* __restrict__ ob) {
  const size_t i = ((size_t)blockIdx.x * 256 + threadIdx.x) * 4;
  float4 va = *reinterpret_cast<const float4*>(a + i);
  float4 vb = *reinterpret_cast<const float4*>(b + i);
  u16x4 ua, ub;
  ua[0] = f2bf(va.x); ua[1] = f2bf(va.y); ua[2] = f2bf(va.z); ua[3] = f2bf(va.w);
  ub[0] = f2bf(vb.x); ub[1] = f2bf(vb.y); ub[2] = f2bf(vb.z); ub[3] = f2bf(vb.w);
  *reinterpret_cast<u16x4*>(oa + i) = ua;
  *reinterpret_cast<u16x4*>(ob + i) = ub;
}

// async 16B global->LDS copy (wave-uniform LDS base + lane*16)
__device__ __forceinline__ void async_cp16(const u16* g, u16* l) {
  __builtin_amdgcn_global_load_lds(
      (const __attribute__((address_space(1))) void*)g,
      (__attribute__((address_space(3))) void*)l, 16, 0, 0);
}

// Inline-asm ds_read_b128: opaque to the backend's LDS-DMA hazard tracking
// (round-3 verified: removed compiler vmcnt drains, 235->182.5us). All lgkm
// ordering is manual (BAR1_WAIT: lgkmcnt(0) + sched_barrier(0), rule #18).
__device__ __forceinline__ short8 ldsr(const lds_u16* p) {
  short8 r;
  asm volatile("ds_read_b128 %0, %1" : "=v"(r) : "v"(p));
  return r;
}

// 256x256 GEMM (NT: A[M,K], B[N,K] row-major, dist = A.B^T), fused smooth-
// chamfer epilogue. Round-4 structure: 32x32x16 MFMA (m119: 2495 vs 2075 TF
// pipe rate, half the instruction count) + 2 phases/K-tile (4 barriers/K-tile
// instead of 8; ~32 MFMA-equivalents per barrier, AITER-like amortization).
// 8 waves (2Mx4N), per-wave C = 128x64 as 4x2 tiles of 32x32.
// LDS = 2 buf x (A 256x64 + B 256x64) bf16 = 128 KiB (dynamic).
//
// LDS swizzle (verified round 2/3: SQ_LDS_BANK_CONFLICT = 0): logical
// (row, 8-u16 chunk c) lives at LDS[row][c ^ (row&7)]. Applied BOTH sides
// (rule #21): inverse-swizzled GLOBAL source (LDS dest linear for
// global_load_lds) + swizzled ds_read chunk. 32x32 frag rows are
// base + (lane&31) -> row&7 = lane&7: same conflict-free shape.
__global__ __launch_bounds__(512, 2) void gemm_chamfer(
    const u16* __restrict__ A, const u16* __restrict__ B, float* __restrict__ out) {
  extern __shared__ __align__(16) u16 sm[];   // 131072 B
  lds_u16* const smb = (lds_u16*)sm;

  const int tid  = threadIdx.x;
  const int lane = tid & 63;
  const int wave = tid >> 6;
  const int wm = wave >> 2;       // 0..1  (row half of block tile)
  const int wn = wave & 3;        // 0..3  (col quarter)
  const int l31 = lane & 31;
  const int el7 = lane & 7;
  const int hi5 = lane >> 5;

  // XCD-aware bijective swizzle: nwg=1024, 8 XCDs -> 128 consecutive tiles/XCD
  const int bid = (int)blockIdx.x;
  const int swz = (bid & 7) * 128 + (bid >> 3);
  const int bm0 = (swz >> 5) * BM;
  const int bn0 = (swz & 31) * BN;

  // ---- staging map (unchanged, verified): thread t -> row t>>3 of a 64-row
  // chunk, 16B chunk t&7; source chunk pre-XOR'd by (row&7); LDS dest linear.
  const int sr8 = tid >> 3;
  const int kx  = (((tid & 7) ^ (sr8 & 7)) * 8);
  const u16* aG = A + (size_t)(bm0 + sr8) * DIM + kx;
  const u16* bG = B + (size_t)(bn0 + sr8) * DIM + kx;
  const int ldst = tid * 8;

#define STAGE(gbase, lbuf, X, h)                                              \
  do {                                                                        \
    const u16* _g = (gbase) + ((h) ? (size_t)128 * DIM : 0) + (size_t)(X) * BK; \
    u16* _l = (lbuf) + (h) * 8192 + ldst;                                     \
    async_cp16(_g, _l);                                                       \
    async_cp16(_g + (size_t)64 * DIM, _l + 4096);                             \
  } while (0)

  // ---- fragment-read constants (32x32x16: lane holds row=base+(lane&31),
  // k = ks*16 + (lane>>5)*8 + j  ->  8-u16 chunk index = (ks<<1)|hi5).
  int cks[4];
#pragma unroll
  for (int ks = 0; ks < 4; ++ks) cks[ks] = ((((ks << 1) | hi5) ^ el7) << 3);
  const int aR = (wm * 128 + l31) * 64;         // per-lane A row base (elems)
  const int bR = (wn * 64 + l31) * 64;          // per-lane B row base (elems)

  f32x16 acc[4][2] = {};      // 128 VGPR: [tm 0..3][tn 0..1] 32x32 tiles
  short8 af[4][2];            // A frags [ks][i] for current phase's 2 tile-rows
  short8 bf[4][2];            // B frags [ks][tn] (read once per K-tile at P1)

  u16* const buf0A = sm;
  u16* const buf0B = sm + 16384;
  u16* const buf1A = sm + 32768;
  u16* const buf1B = sm + 49152;

  // ---- prologue: tile0 A+B (8 loads) + tile1 B (4 loads); A(1) staged at
  // u=0.P1 (steady-state). vmcnt(4) -> tile0's 8 oldest landed.
  STAGE(aG, buf0A, 0, 0); STAGE(aG, buf0A, 0, 1);
  STAGE(bG, buf0B, 0, 0); STAGE(bG, buf0B, 0, 1);
  STAGE(bG, buf1B, 1, 0); STAGE(bG, buf1B, 1, 1);
  asm volatile("s_waitcnt vmcnt(4)" ::: "memory");
  __builtin_amdgcn_s_barrier();

  // phase h reads A tile-rows {2h, 2h+1} (rows wm*128 + (2h+i)*32 + l31)
#define LOAD_A32(abase, h)                                                    \
  _Pragma("unroll")                                                           \
  for (int i = 0; i < 2; ++i)                                                 \
    _Pragma("unroll")                                                         \
    for (int ks = 0; ks < 4; ++ks)                                            \
      af[ks][i] = ldsr(smb + (abase) + aR + (2 * (h) + i) * 2048 + cks[ks]);

#define LOAD_B32(bbase)                                                       \
  _Pragma("unroll")                                                           \
  for (int tn = 0; tn < 2; ++tn)                                              \
    _Pragma("unroll")                                                         \
    for (int ks = 0; ks < 4; ++ks)                                            \
      bf[ks][tn] = ldsr(smb + (bbase) + bR + tn * 2048 + cks[ks]);

#define MFMA_H(h)                                                             \
  _Pragma("unroll")                                                           \
  for (int i = 0; i < 2; ++i)                                                 \
    _Pragma("unroll")                                                         \
    for (int tn = 0; tn < 2; ++tn)                                            \
      _Pragma("unroll")                                                       \
      for (int ks = 0; ks < 4; ++ks)                                          \
        acc[2 * (h) + i][tn] = __builtin_amdgcn_mfma_f32_32x32x16_bf16(       \
            af[ks][i], bf[ks][tn], acc[2 * (h) + i][tn], 0, 0, 0);

#define BAR1_WAIT()                                                           \
  __builtin_amdgcn_s_barrier();                                               \
  asm volatile("s_waitcnt lgkmcnt(0)" ::: "memory");                          \
  __builtin_amdgcn_sched_barrier(0)

  // K-loop, 2 phases/K-tile. Staging (race-audited): P1 stages A(u+1)->nxtA
  // (nxtA holds tile u-1's A, reads finished last tile); P2 stages B(u+2)
  // ->curB (all B reads happen in P1; barrier between). Boundary vmcnt(4)
  // waits A(u+1)+B(u+1) landed, keeps B(u+2) (4 loads) in flight.
#pragma unroll 2
  for (int u = 0; u < KTILES; ++u) {
    const int abase = (u & 1) * 32768;
    const int bbase = abase + 16384;
    u16* const curB = sm + bbase;
    u16* const nxtA = sm + (abase ^ 32768);

    // ---- P1: read A-half0 (8) + all B (8); stage A(u+1)
    LOAD_A32(abase, 0);
    LOAD_B32(bbase);
    if (u + 1 < KTILES) { STAGE(aG, nxtA, u + 1, 0); STAGE(aG, nxtA, u + 1, 1); }
    asm volatile("s_waitcnt lgkmcnt(8)" ::: "memory");   // pre-drain (16 reads)
    BAR1_WAIT();
    __builtin_amdgcn_s_setprio(1);
    MFMA_H(0);
    __builtin_amdgcn_s_setprio(0);
    __builtin_amdgcn_s_barrier();

    // ---- P2: read A-half1 (8); stage B(u+2) (B reads done at P1)
    LOAD_A32(abase, 1);
    if (u + 2 < KTILES) { STAGE(bG, curB, u + 2, 0); STAGE(bG, curB, u + 2, 1); }
    BAR1_WAIT();
    __builtin_amdgcn_s_setprio(1);
    MFMA_H(1);
    __builtin_amdgcn_s_setprio(0);
    if (u < KTILES - 2) asm volatile("s_waitcnt vmcnt(4)" ::: "memory");
    else                asm volatile("s_waitcnt vmcnt(0)" ::: "memory");
    __builtin_amdgcn_s_barrier();
  }

  // ---- fused chamfer epilogue. 32x32 C/D layout (m74/m101 verified):
  // col = lane&31, row = (reg&3) + 8*(reg>>2) + 4*(lane>>5). Img-set = 4
  // consecutive regs (4p..4p+3) in-lane; txt-set = 4 consecutive cols =
  // shfl_xor over lanes 1,2 (stays within the lane>>5 half).
#pragma unroll
  for (int tm = 0; tm < 4; ++tm) {
#pragma unroll
    for (int tn = 0; tn < 2; ++tn) {
      f32x16 c = acc[tm][tn];
#pragma unroll
      for (int p = 0; p < 4; ++p) {
        float e0 = __expf(16.0f * c[4 * p + 0]);
        float e1 = __expf(16.0f * c[4 * p + 1]);
        float e2 = __expf(16.0f * c[4 * p + 2]);
        float e3 = __expf(16.0f * c[4 * p + 3]);
        // left partial: log of sum over the 4 img-set rows (in-lane), per col
        float l = __logf(e0 + e1 + e2 + e3);
        // right: per-row sums over the 4 txt-set cols (cross-lane)
        e0 += __shfl_xor(e0, 1); e0 += __shfl_xor(e0, 2);
        e1 += __shfl_xor(e1, 1); e1 += __shfl_xor(e1, 2);
        e2 += __shfl_xor(e2, 1); e2 += __shfl_xor(e2, 2);
        e3 += __shfl_xor(e3, 1); e3 += __shfl_xor(e3, 2);
        float r = __logf(e0) + __logf(e1) + __logf(e2) + __logf(e3);
        // left: sum the per-col logs over the 4 txt-set cols
        l += __shfl_xor(l, 1); l += __shfl_xor(l, 2);
        if ((lane & 3) == 0) {
          const int obi = ((bm0 + wm * 128 + tm * 32) >> 2) + 2 * p + hi5;
          const int obt = ((bn0 + wn * 64 + tn * 32) >> 2) + (l31 >> 2);
          out[(size_t)obi * BOUT + obt] = (r + l) * 0.0078125f;  // /128
        }
      }
    }
  }
}

extern "C" void kernel_launch(void* const* d_in, const int* in_sizes, int n_in,
                              void* d_out, int out_size, void* d_ws, size_t ws_size,
                              hipStream_t stream) {
  const float* img = (const float*)d_in[0];
  const float* txt = (const float*)d_in[1];
  float* out = (float*)d_out;
  u16* bA = (u16*)d_ws;                       // 16 MiB
  u16* bB = bA + (size_t)N_ROWS * DIM;        // 16 MiB

  const int nPer = N_ROWS * DIM;              // 8388608 per input
  cast_kernel<<<dim3(nPer / (256 * 4)), dim3(256), 0, stream>>>(img, txt, bA, bB);

  static bool attr_set = false;
  if (!attr_set) {
    hipFuncSetAttribute((const void*)gemm_chamfer,
                        hipFuncAttributeMaxDynamicSharedMemorySize, 131072);
    attr_set = true;
  }
  dim3 ggrid(N_ROWS / BM * (N_ROWS / BN));    // 1024 blocks (32x32 tiles)
  gemm_chamfer<<<ggrid, dim3(512), 131072, stream>>>(bA, bB, out);
}

// Round 6
// 265.523 us; speedup vs baseline: 1.0393x; 1.0393x over previous
//
#include <hip/hip_runtime.h>

// Problem constants (fixed by the reference):
//   img [8192,1024] f32, txt [8192,1024] f32, both l2-normalized
//   set sizes si=st=4, t=16, tts=1, DENOM=2  -> out[bi][bt] = (right+left)/128
#define N_ROWS 8192
#define DIM    1024
#define BOUT   2048
#define BM 128
#define BN 128
#define BK 32
#define KTILES (DIM / BK)   // 32

typedef unsigned short u16;
typedef __attribute__((ext_vector_type(4))) unsigned short u16x4;
typedef __attribute__((ext_vector_type(8))) short short8;   // 8 bf16 MFMA A/B frag
typedef __attribute__((ext_vector_type(4))) float f32x4;    // MFMA C/D frag
typedef __attribute__((address_space(3))) u16 lds_u16;

// fp32 -> bf16 round-to-nearest-even
__device__ __forceinline__ u16 f2bf(float f) {
  unsigned u = __float_as_uint(f);
  u += 0x7fffu + ((u >> 16) & 1u);
  return (u16)(u >> 16);
}

__global__ void cast_kernel(const float* __restrict__ a, const float* __restrict__ b,
                            u16* __restrict__ oa, u16* __restrict__ ob) {
  const size_t i = ((size_t)blockIdx.x * 256 + threadIdx.x) * 4;
  float4 va = *reinterpret_cast<const float4*>(a + i);
  float4 vb = *reinterpret_cast<const float4*>(b + i);
  u16x4 ua, ub;
  ua[0] = f2bf(va.x); ua[1] = f2bf(va.y); ua[2] = f2bf(va.z); ua[3] = f2bf(va.w);
  ub[0] = f2bf(vb.x); ub[1] = f2bf(vb.y); ub[2] = f2bf(vb.z); ub[3] = f2bf(vb.w);
  *reinterpret_cast<u16x4*>(oa + i) = ua;
  *reinterpret_cast<u16x4*>(ob + i) = ub;
}

// async 16B global->LDS copy (wave-uniform LDS base + lane*16)
__device__ __forceinline__ void async_cp16(const u16* g, u16* l) {
  __builtin_amdgcn_global_load_lds(
      (const __attribute__((address_space(1))) void*)g,
      (__attribute__((address_space(3))) void*)l, 16, 0, 0);
}

// Inline-asm ds_read_b128: opaque to the backend's LDS-DMA hazard tracker, so
// it cannot insert conservative `s_waitcnt vmcnt(0)` before reads that alias
// in-flight global_load_lds destinations (verified +29% in round 3; this
// hazard is what serialized the round-0 double buffer). All ordering manual:
// lgkmcnt(0) + sched_barrier(0) before consuming (rule #18).
__device__ __forceinline__ short8 ldsr(const lds_u16* p) {
  short8 r;
  asm volatile("ds_read_b128 %0, %1" : "=v"(r) : "v"(p));
  return r;
}

// 128x128 GEMM (NT: A[M,K], B[N,K] row-major, dist = A.B^T), fused smooth-
// chamfer epilogue. Structure (round-5 intent, round-6 fixes the LDS OOB):
// m97/m103-proven 128²/BK=32 multi-block design (912 TF @K=4096 precedent) +
// TRUE double-buffering enabled by asm ds_read + manual counted waits.
// 4 waves (2x2), per-wave 64x64 (4x4 tiles of 16x16x32). LDS layout in u16
// units (round-5 bug: offsets were bytes applied to u16* -> buffer 1 was
// entirely OOB, odd K-tiles read as 0, absmax 0.033 ≈ half-dist error):
//   buf bc at bc*8192; A at +0 (4096 u16), B at +4096 (4096 u16). 32 KiB.
// __launch_bounds__(256,3) -> 3 blocks/CU; cross-block phase diversity hides
// per-iteration drains (m114: co-resident MFMA/VALU ≈ max, not sum).
// Linear LDS [row][32]: benign bank pattern (m97/m98: ~1.7e7 conflict count
// coexists with 874-912 TF; no swizzle).
__global__ __launch_bounds__(256, 3) void gemm_chamfer(
    const u16* __restrict__ A, const u16* __restrict__ B, float* __restrict__ out) {
  __shared__ __align__(16) u16 lds[2][2][BM * BK];   // [buf][A/B][4096] = 32 KiB
  lds_u16* const smb = (lds_u16*)&lds[0][0][0];
  u16* const lbase = &lds[0][0][0];

  const int tid  = threadIdx.x;
  const int lane = tid & 63;
  const int wave = tid >> 6;
  const int wm = wave & 1;          // wave row (64 rows)
  const int wn = wave >> 1;         // wave col (64 cols)
  const int lm = lane & 15;
  const int lq = lane >> 4;

  // XCD-aware bijective swizzle: 4096 blocks, 8 XCDs -> 512 consecutive tiles
  // (8 full block-rows) per XCD; A-panel working set 2 MB fits the 4 MB L2.
  const int bid = (int)blockIdx.x;
  const int swz = (bid & 7) * 512 + (bid >> 3);
  const int bm0 = (swz >> 6) * BM;
  const int bn0 = (swz & 63) * BN;

  // staging map: thread t -> row t>>2 (and +64), 8-elem k-chunk (t&3)*8.
  // LDS dest offset = tid*8 u16 (wave-uniform base + lane*16B) ✓ linear.
  const int ldrow = tid >> 2;
  const int ldk   = (tid & 3) * 8;
  const u16* aSrc = A + (size_t)(bm0 + ldrow) * DIM + ldk;
  const u16* bSrc = B + (size_t)(bn0 + ldrow) * DIM + ldk;
  const int dstOff = ldrow * BK + ldk;       // == tid*8, in [0,2048)
  const size_t half = (size_t)64 * DIM;

  // stage K-tile t into buffer bc (A 8 KiB + B 8 KiB = 4 x cp16/thread).
  // All offsets in u16 elements: buffer stride 8192, A rows 64..127 at +2048,
  // B region at +4096.
#define STAGE(bc, t)                                                          \
  do {                                                                        \
    const int _k = (t) * BK;                                                  \
    u16* _la = lbase + (bc) * 8192 + dstOff;                                  \
    u16* _lb = _la + 4096;                                                    \
    async_cp16(aSrc + _k,        _la);                                        \
    async_cp16(aSrc + _k + half, _la + 2048);                                 \
    async_cp16(bSrc + _k,        _lb);                                        \
    async_cp16(bSrc + _k + half, _lb + 2048);                                 \
  } while (0)

  // fragment-read bases (u16 offsets from smb); frag row = wm*64+mt*16+lm
  const int aFrag = (wm * 64 + lm) * BK + lq * 8;
  const int bFrag = 4096 + (wn * 64 + lm) * BK + lq * 8;

  f32x4 acc[4][4] = {};
  short8 af[4], bf[4];

  // ---- prologue: tile 0 -> buf 0
  STAGE(0, 0);
  asm volatile("s_waitcnt vmcnt(0)" ::: "memory");
  __builtin_amdgcn_s_barrier();

  // ---- K-loop: one barrier per K-tile; loads for t+1 in flight during the
  // reads+MFMA of t; vmcnt(0) placed AFTER the MFMA convoy (loads have the
  // whole read+MFMA window, plus 2 other resident blocks, to land).
  // Race audit: reads of buf[cur] drain at lgkmcnt(0) BEFORE the barrier that
  // precedes overwriting buf[cur] (next iter's STAGE); buf[nxt] writes drain
  // at vmcnt(0) BEFORE the barrier that precedes reading buf[nxt].
#pragma unroll 2
  for (int t = 0; t < KTILES; ++t) {
    const int cur = (t & 1) * 8192;
    if (t + 1 < KTILES) STAGE((t & 1) ^ 1, t + 1);

#pragma unroll
    for (int mt = 0; mt < 4; ++mt) af[mt] = ldsr(smb + cur + aFrag + mt * 16 * BK);
#pragma unroll
    for (int nt = 0; nt < 4; ++nt) bf[nt] = ldsr(smb + cur + bFrag + nt * 16 * BK);

    asm volatile("s_waitcnt lgkmcnt(0)" ::: "memory");
    __builtin_amdgcn_sched_barrier(0);
    __builtin_amdgcn_s_setprio(1);
#pragma unroll
    for (int mt = 0; mt < 4; ++mt)
#pragma unroll
      for (int nt = 0; nt < 4; ++nt)
        acc[mt][nt] = __builtin_amdgcn_mfma_f32_16x16x32_bf16(af[mt], bf[nt], acc[mt][nt], 0, 0, 0);
    __builtin_amdgcn_s_setprio(0);

    asm volatile("s_waitcnt vmcnt(0)" ::: "memory");
    __builtin_amdgcn_s_barrier();
  }

  // ---- fused chamfer epilogue (verbatim from the verified 128² kernel).
  // C layout: col = lane&15, row = lq*4 + reg; set blocks 4-aligned both dims.
#pragma unroll
  for (int mt = 0; mt < 4; ++mt) {
#pragma unroll
    for (int nt = 0; nt < 4; ++nt) {
      f32x4 c = acc[mt][nt];
      float e0 = __expf(16.0f * c[0]);
      float e1 = __expf(16.0f * c[1]);
      float e2 = __expf(16.0f * c[2]);
      float e3 = __expf(16.0f * c[3]);
      // left partial: log of sum over the 4 img-set rows (in-lane), per column
      float l = __logf(e0 + e1 + e2 + e3);
      // right: per-row sums over the 4 txt-set columns (cross-lane)
      e0 += __shfl_xor(e0, 1); e0 += __shfl_xor(e0, 2);
      e1 += __shfl_xor(e1, 1); e1 += __shfl_xor(e1, 2);
      e2 += __shfl_xor(e2, 1); e2 += __shfl_xor(e2, 2);
      e3 += __shfl_xor(e3, 1); e3 += __shfl_xor(e3, 2);
      float r = __logf(e0) + __logf(e1) + __logf(e2) + __logf(e3);
      // left: sum the per-column logs over the 4 txt-set columns
      l += __shfl_xor(l, 1); l += __shfl_xor(l, 2);
      if ((lane & 3) == 0) {
        const int obi = ((bm0 + wm * 64 + mt * 16) >> 2) + lq;
        const int obt = ((bn0 + wn * 64 + nt * 16) >> 2) + (lm >> 2);
        out[(size_t)obi * BOUT + obt] = (r + l) * 0.0078125f;  // /128
      }
    }
  }
}

extern "C" void kernel_launch(void* const* d_in, const int* in_sizes, int n_in,
                              void* d_out, int out_size, void* d_ws, size_t ws_size,
                              hipStream_t stream) {
  const float* img = (const float*)d_in[0];
  const float* txt = (const float*)d_in[1];
  float* out = (float*)d_out;
  u16* bA = (u16*)d_ws;                       // 16 MiB
  u16* bB = bA + (size_t)N_ROWS * DIM;        // 16 MiB

  const int nPer = N_ROWS * DIM;              // 8388608 per input
  cast_kernel<<<dim3(nPer / (256 * 4)), dim3(256), 0, stream>>>(img, txt, bA, bB);

  dim3 ggrid((N_ROWS / BM) * (N_ROWS / BN));  // 4096 blocks (64x64 tiles)
  gemm_chamfer<<<ggrid, dim3(256), 0, stream>>>(bA, bB, out);
}